// Round 1
// baseline (188.944 us; speedup 1.0000x reference)
//
#include <hip/hip_runtime.h>

typedef __attribute__((ext_vector_type(8))) short short8;
typedef __attribute__((ext_vector_type(4))) short short4v;
typedef __attribute__((ext_vector_type(4))) float f32x4;

__device__ __forceinline__ short f2bf(float f) {
  unsigned u = __builtin_bit_cast(unsigned, f);
  u = u + 0x7fffu + ((u >> 16) & 1u);
  return (short)(u >> 16);
}
__device__ __forceinline__ float bf2f(short s) {
  unsigned u = ((unsigned)(unsigned short)s) << 16;
  return __builtin_bit_cast(float, u);
}

// ---------------------------------------------------------------- weights cast
__global__ __launch_bounds__(256) void wcast_kernel(
    const float* __restrict__ wq, const float* __restrict__ wk,
    const float* __restrict__ wv, const float* __restrict__ wp,
    short* __restrict__ out) {
  int i = blockIdx.x * 256 + threadIdx.x;  // grid 1024 -> 262144 threads
  out[i]          = f2bf(wq[i]);
  out[262144 + i] = f2bf(wk[i]);
  out[524288 + i] = f2bf(wv[i]);
  out[786432 + i] = f2bf(wp[i]);
}

// ---------------------------------------------------------------- GroupNorm
// x[B=16,C=512,N=1024] f32 -> xn_t[B,N,C] bf16 (token-major), per (b,g) block.
__global__ __launch_bounds__(256) void groupnorm_kernel(
    const float* __restrict__ x, const float* __restrict__ gamma,
    const float* __restrict__ beta, short* __restrict__ xnt) {
  const int bg = blockIdx.x, b = bg >> 3, g = bg & 7;
  const float* base = x + (long)(b * 512 + g * 64) * 1024;  // contiguous 65536 f32
  const int t = threadIdx.x;
  float s = 0.f, ss = 0.f;
  for (int i = t; i < 16384; i += 256) {
    float4 v = ((const float4*)base)[i];
    s  += v.x + v.y + v.z + v.w;
    ss += v.x * v.x + v.y * v.y + v.z * v.z + v.w * v.w;
  }
  __shared__ float rs[4], rss[4];
  for (int o = 32; o > 0; o >>= 1) { s += __shfl_xor(s, o, 64); ss += __shfl_xor(ss, o, 64); }
  if ((t & 63) == 0) { rs[t >> 6] = s; rss[t >> 6] = ss; }
  __syncthreads();
  s  = rs[0] + rs[1] + rs[2] + rs[3];
  ss = rss[0] + rss[1] + rss[2] + rss[3];
  const float mean = s * (1.f / 65536.f);
  const float var  = ss * (1.f / 65536.f) - mean * mean;
  const float rstd = rsqrtf(var + 1e-5f);
  const int cl = t & 63;
  const float ga = gamma[g * 64 + cl] * rstd;
  const float be = beta[g * 64 + cl] - mean * ga;  // y = v*ga + be
  __shared__ float tile[64][65];
  short* outb = xnt + (long)b * 1024 * 512 + g * 64;
  for (int nt = 0; nt < 16; ++nt) {
    const int n0t = nt * 64;
    __syncthreads();
#pragma unroll
    for (int cc = 0; cc < 4; ++cc) {
      int c = (t >> 4) + cc * 16;
      float4 v = *(const float4*)(base + (long)c * 1024 + n0t + (t & 15) * 4);
      tile[c][(t & 15) * 4 + 0] = v.x;
      tile[c][(t & 15) * 4 + 1] = v.y;
      tile[c][(t & 15) * 4 + 2] = v.z;
      tile[c][(t & 15) * 4 + 3] = v.w;
    }
    __syncthreads();
#pragma unroll
    for (int tt = 0; tt < 16; ++tt) {
      int tok = (t >> 6) * 16 + tt;
      float v = tile[cl][tok];
      outb[(long)(n0t + tok) * 512 + cl] = f2bf(v * ga + be);
    }
  }
}

// ---------------------------------------------------------------- row softmax
// In-place over bf16 S rows of 1024. One block (256 thr) per row.
__global__ __launch_bounds__(256) void softmax_kernel(short* __restrict__ S) {
  const long row = blockIdx.x;
  short* p = S + row * 1024;
  const int t = threadIdx.x;
  short4v v4 = *(short4v*)(p + t * 4);
  float v0 = bf2f(v4.x), v1 = bf2f(v4.y), v2 = bf2f(v4.z), v3 = bf2f(v4.w);
  float m = fmaxf(fmaxf(v0, v1), fmaxf(v2, v3));
  __shared__ float red[4], red2[4];
  for (int o = 32; o > 0; o >>= 1) m = fmaxf(m, __shfl_xor(m, o, 64));
  if ((t & 63) == 0) red[t >> 6] = m;
  __syncthreads();
  m = fmaxf(fmaxf(red[0], red[1]), fmaxf(red[2], red[3]));
  float e0 = __expf(v0 - m), e1 = __expf(v1 - m), e2 = __expf(v2 - m), e3 = __expf(v3 - m);
  float s = e0 + e1 + e2 + e3;
  for (int o = 32; o > 0; o >>= 1) s += __shfl_xor(s, o, 64);
  if ((t & 63) == 0) red2[t >> 6] = s;
  __syncthreads();
  s = red2[0] + red2[1] + red2[2] + red2[3];
  float inv = 1.f / s;
  short4v o4;
  o4.x = f2bf(e0 * inv); o4.y = f2bf(e1 * inv); o4.z = f2bf(e2 * inv); o4.w = f2bf(e3 * inv);
  *(short4v*)(p + t * 4) = o4;
}

// ---------------------------------------------------------------- GEMM (bt)
// C[M,N] = A[M,K] * Bt[N,K]^T  (both bf16 row-major, lda=ldb=K), batched over z.
// 128x128 tile, BK=64, 4 waves (2x2), each wave 64x64 via 4x4 mfma 16x16x32.
// LDS staged via global_load_lds w=16, XOR-swizzled (pre-swizzled global src).
#define BM 128
#define BK 64
enum { EPI_TRANS_BF16 = 0, EPI_NORM_BF16 = 1, EPI_RES_F32 = 2 };

__device__ __forceinline__ int swz_idx(int row, int k) {  // short-element index
  return row * 64 + ((((k >> 3) ^ row) & 7) << 3) + (k & 7);
}

template <int EPI>
__global__ __launch_bounds__(256, 2) void gemm_bt(
    const short* __restrict__ A, const short* __restrict__ Bt,
    void* __restrict__ Cv, const float* __restrict__ bias,
    const float* __restrict__ resid, float scale,
    int M, int N, int K, long aStr, long bStr, long cStr, long rStr) {
  __shared__ short lds[2 * BM * BK];  // [0..8191]=A-tile, [8192..]=B-tile
  const int b = blockIdx.z;
  const short* Ab = A + (long)b * aStr;
  const short* Bb = Bt + (long)b * bStr;
  const int m0 = blockIdx.y * BM, n0 = blockIdx.x * BM;
  const int tid = threadIdx.x, lane = tid & 63, w = tid >> 6;
  const int wm = (w >> 1) * 64, wn = (w & 1) * 64;
  f32x4 acc[4][4] = {};

  const int rowst = (w * 4) * 8 + (lane >> 3);  // staging row base for it=0
  for (int k0 = 0; k0 < K; k0 += BK) {
    __syncthreads();
#pragma unroll
    for (int it = 0; it < 4; ++it) {
      int ci = w * 4 + it;
      int row = rowst + it * 8;
      int slot = (lane & 7) ^ (row & 7);
      const short* ga = Ab + (long)(m0 + row) * K + k0 + slot * 8;
      __builtin_amdgcn_global_load_lds(
          (const __attribute__((address_space(1))) void*)ga,
          (__attribute__((address_space(3))) void*)(lds + ci * 512), 16, 0, 0);
      const short* gb = Bb + (long)(n0 + row) * K + k0 + slot * 8;
      __builtin_amdgcn_global_load_lds(
          (const __attribute__((address_space(1))) void*)gb,
          (__attribute__((address_space(3))) void*)(lds + 8192 + ci * 512), 16, 0, 0);
    }
    __syncthreads();
#pragma unroll
    for (int kk = 0; kk < 2; ++kk) {
      short8 af[4], bf[4];
      const int kf = kk * 32 + (lane >> 4) * 8;
#pragma unroll
      for (int i = 0; i < 4; ++i) {
        af[i] = *(const short8*)(lds + swz_idx(wm + i * 16 + (lane & 15), kf));
        bf[i] = *(const short8*)(lds + 8192 + swz_idx(wn + i * 16 + (lane & 15), kf));
      }
#pragma unroll
      for (int i = 0; i < 4; ++i)
#pragma unroll
        for (int j = 0; j < 4; ++j)
          acc[i][j] = __builtin_amdgcn_mfma_f32_16x16x32_bf16(af[i], bf[j], acc[i][j], 0, 0, 0);
    }
  }

  const int mb = m0 + wm + (lane >> 4) * 4;  // + i*16 (+r)
  const int nb = n0 + wn + (lane & 15);      // + j*16
  if constexpr (EPI == EPI_TRANS_BF16) {
    // C^T layout [N][M]: 4 consecutive m per lane -> packed 8B store
    short* C = (short*)Cv + (long)b * cStr;
#pragma unroll
    for (int i = 0; i < 4; ++i) {
      int m = mb + i * 16;
      float b0 = bias[m], b1 = bias[m + 1], b2 = bias[m + 2], b3 = bias[m + 3];
#pragma unroll
      for (int j = 0; j < 4; ++j) {
        int n = nb + j * 16;
        short4v o;
        o.x = f2bf(acc[i][j][0] + b0);
        o.y = f2bf(acc[i][j][1] + b1);
        o.z = f2bf(acc[i][j][2] + b2);
        o.w = f2bf(acc[i][j][3] + b3);
        *(short4v*)(C + (long)n * M + m) = o;
      }
    }
  } else if constexpr (EPI == EPI_NORM_BF16) {
    short* C = (short*)Cv + (long)b * cStr;
#pragma unroll
    for (int i = 0; i < 4; ++i) {
#pragma unroll
      for (int r = 0; r < 4; ++r) {
        int m = mb + i * 16 + r;
        float bi = bias ? bias[m] : 0.f;
#pragma unroll
        for (int j = 0; j < 4; ++j) {
          int n = nb + j * 16;
          C[(long)m * N + n] = f2bf(acc[i][j][r] * scale + bi);
        }
      }
    }
  } else {  // EPI_RES_F32
    float* C = (float*)Cv + (long)b * cStr;
    const float* R = resid + (long)b * rStr;
#pragma unroll
    for (int i = 0; i < 4; ++i) {
#pragma unroll
      for (int r = 0; r < 4; ++r) {
        int m = mb + i * 16 + r;
        float bi = bias[m];
#pragma unroll
        for (int j = 0; j < 4; ++j) {
          int n = nb + j * 16;
          C[(long)m * N + n] = acc[i][j][r] + bi + R[(long)m * N + n];
        }
      }
    }
  }
}

// ---------------------------------------------------------------- launch
extern "C" void kernel_launch(void* const* d_in, const int* in_sizes, int n_in,
                              void* d_out, int out_size, void* d_ws, size_t ws_size,
                              hipStream_t stream) {
  const float* x     = (const float*)d_in[0];
  const float* gamma = (const float*)d_in[1];
  const float* beta  = (const float*)d_in[2];
  const float* wq    = (const float*)d_in[3];
  const float* bq    = (const float*)d_in[4];
  const float* wk    = (const float*)d_in[5];
  const float* bk    = (const float*)d_in[6];
  const float* wv    = (const float*)d_in[7];
  const float* bv    = (const float*)d_in[8];
  const float* wp    = (const float*)d_in[9];
  const float* bp    = (const float*)d_in[10];

  char* ws = (char*)d_ws;
  short* wbf = (short*)ws;                       // 4 x 262144 shorts (2 MB)
  short* xnt = (short*)(ws + 2097152l);          // [B,N,C] bf16, 16 MB
  short* q_t = (short*)(ws + 18874368l);         // [B,N,C]
  short* k_t = (short*)(ws + 35651584l);         // [B,N,C]
  short* vbf = (short*)(ws + 52428800l);         // [B,C,N]
  short* Sbf = (short*)(ws + 69206016l);         // [B,N,N] bf16, 33.5 MB
  short* h_t = xnt;                              // alias (xn dead after v-GEMM)

  wcast_kernel<<<1024, 256, 0, stream>>>(wq, wk, wv, wp, wbf);
  groupnorm_kernel<<<128, 256, 0, stream>>>(x, gamma, beta, xnt);

  const float iscale = 0.044194173824159216f;  // 1/sqrt(512)
  // q_t = (wq . xn^T)^T + bq ; k_t likewise ; v = wv . xn^T + bv
  gemm_bt<EPI_TRANS_BF16><<<dim3(8, 4, 16), 256, 0, stream>>>(
      wbf, xnt, q_t, bq, nullptr, 1.f, 512, 1024, 512, 0, 524288, 524288, 0);
  gemm_bt<EPI_TRANS_BF16><<<dim3(8, 4, 16), 256, 0, stream>>>(
      wbf + 262144, xnt, k_t, bk, nullptr, 1.f, 512, 1024, 512, 0, 524288, 524288, 0);
  gemm_bt<EPI_NORM_BF16><<<dim3(8, 4, 16), 256, 0, stream>>>(
      wbf + 524288, xnt, vbf, bv, nullptr, 1.f, 512, 1024, 512, 0, 524288, 524288, 0);
  // S = (q_t . k_t^T) * scale
  gemm_bt<EPI_NORM_BF16><<<dim3(8, 8, 16), 256, 0, stream>>>(
      q_t, k_t, Sbf, nullptr, nullptr, iscale, 1024, 1024, 512, 524288, 524288, 1048576, 0);
  softmax_kernel<<<16384, 256, 0, stream>>>(Sbf);
  // h_t = P . v^T
  gemm_bt<EPI_NORM_BF16><<<dim3(4, 8, 16), 256, 0, stream>>>(
      Sbf, vbf, h_t, nullptr, nullptr, 1.f, 1024, 512, 1024, 1048576, 524288, 524288, 0);
  // out = wp . h_t^T + bp + x
  gemm_bt<EPI_RES_F32><<<dim3(8, 4, 16), 256, 0, stream>>>(
      wbf + 786432, h_t, d_out, bp, x, 1.f, 512, 1024, 512, 0, 524288, 524288, 524288);
}

// Round 2
// 165.164 us; speedup vs baseline: 1.1440x; 1.1440x over previous
//
#include <hip/hip_runtime.h>

typedef __attribute__((ext_vector_type(8))) short short8;
typedef __attribute__((ext_vector_type(4))) short short4v;
typedef __attribute__((ext_vector_type(4))) float f32x4;

__device__ __forceinline__ short f2bf(float f) {
  unsigned u = __builtin_bit_cast(unsigned, f);
  u = u + 0x7fffu + ((u >> 16) & 1u);
  return (short)(u >> 16);
}
__device__ __forceinline__ float bf2f(short s) {
  unsigned u = ((unsigned)(unsigned short)s) << 16;
  return __builtin_bit_cast(float, u);
}

// ---------------------------------------------------------------- weights cast
__global__ __launch_bounds__(256) void wcast_kernel(
    const float* __restrict__ wq, const float* __restrict__ wk,
    const float* __restrict__ wv, const float* __restrict__ wp,
    short* __restrict__ out) {
  int i = blockIdx.x * 256 + threadIdx.x;  // grid 1024 -> 262144 threads
  out[i]          = f2bf(wq[i]);
  out[262144 + i] = f2bf(wk[i]);
  out[524288 + i] = f2bf(wv[i]);
  out[786432 + i] = f2bf(wp[i]);
}

// ---------------------------------------------------------------- GroupNorm
// Pass 1: partial sums. grid 1024 = (bg 0..127) * 8 chunks; 8192 floats/block.
__global__ __launch_bounds__(256) void gn_stats1(
    const float* __restrict__ x, float2* __restrict__ part) {
  const int blk = blockIdx.x, t = threadIdx.x;
  const float* base = x + (long)blk * 8192;
  float s = 0.f, ss = 0.f;
#pragma unroll
  for (int j = 0; j < 8; ++j) {
    float4 v = ((const float4*)base)[t + j * 256];
    s  += v.x + v.y + v.z + v.w;
    ss += v.x * v.x + v.y * v.y + v.z * v.z + v.w * v.w;
  }
  for (int o = 32; o > 0; o >>= 1) { s += __shfl_xor(s, o, 64); ss += __shfl_xor(ss, o, 64); }
  __shared__ float rs[4], rss[4];
  if ((t & 63) == 0) { rs[t >> 6] = s; rss[t >> 6] = ss; }
  __syncthreads();
  if (t == 0) {
    part[blk] = make_float2(rs[0] + rs[1] + rs[2] + rs[3],
                            rss[0] + rss[1] + rss[2] + rss[3]);
  }
}

// Pass 2: normalize + transpose to xnt[B,N,C] bf16.
// grid 1024 = b(16) x g(8) x nc(8); block handles 64 channels x 128 tokens.
#define TP 133  // LDS tile stride (pad): <=2-way banks on both phases
__global__ __launch_bounds__(256) void gn_norm_t(
    const float* __restrict__ x, const float2* __restrict__ part,
    const float* __restrict__ gamma, const float* __restrict__ beta,
    short* __restrict__ xnt) {
  const int blk = blockIdx.x;
  const int nc = blk & 7, g = (blk >> 3) & 7, b = blk >> 6;
  const int t = threadIdx.x;
  // redundant per-block reduce of 8 partials (broadcast loads, cheap)
  float s = 0.f, ss = 0.f;
#pragma unroll
  for (int j = 0; j < 8; ++j) {
    float2 p = part[(b * 8 + g) * 8 + j];
    s += p.x; ss += p.y;
  }
  const float mean = s * (1.f / 65536.f);
  const float var  = ss * (1.f / 65536.f) - mean * mean;
  const float rstd = rsqrtf(var + 1e-5f);

  const float* base = x + (long)(b * 512 + g * 64) * 1024 + nc * 128;
  __shared__ float tile[64][TP];
  const int row = t >> 2, c4 = t & 3;
#pragma unroll
  for (int j = 0; j < 8; ++j) {
    float4 v = *(const float4*)(base + (long)row * 1024 + (c4 + j * 4) * 4);
    *(float4*)&tile[row][(c4 + j * 4) * 4] = v;
  }
  const int cl4 = (t & 15) * 4;  // channel base within group (store phase)
  float ga[4], be[4];
#pragma unroll
  for (int j = 0; j < 4; ++j) {
    float gm = gamma[g * 64 + cl4 + j];
    ga[j] = gm * rstd;
    be[j] = beta[g * 64 + cl4 + j] - mean * ga[j];
  }
  __syncthreads();
  short* outb = xnt + (long)b * 524288 + (long)(nc * 128) * 512 + g * 64 + cl4;
#pragma unroll
  for (int it = 0; it < 8; ++it) {
    const int tok = (t >> 4) + it * 16;
    short4v o;
    o.x = f2bf(tile[cl4 + 0][tok] * ga[0] + be[0]);
    o.y = f2bf(tile[cl4 + 1][tok] * ga[1] + be[1]);
    o.z = f2bf(tile[cl4 + 2][tok] * ga[2] + be[2]);
    o.w = f2bf(tile[cl4 + 3][tok] * ga[3] + be[3]);
    *(short4v*)(outb + (long)tok * 512) = o;
  }
}

// ---------------------------------------------------------------- row softmax
// In-place over bf16 S rows of 1024. One block (256 thr) per row.
__global__ __launch_bounds__(256) void softmax_kernel(short* __restrict__ S) {
  const long row = blockIdx.x;
  short* p = S + row * 1024;
  const int t = threadIdx.x;
  short4v v4 = *(short4v*)(p + t * 4);
  float v0 = bf2f(v4.x), v1 = bf2f(v4.y), v2 = bf2f(v4.z), v3 = bf2f(v4.w);
  float m = fmaxf(fmaxf(v0, v1), fmaxf(v2, v3));
  __shared__ float red[4], red2[4];
  for (int o = 32; o > 0; o >>= 1) m = fmaxf(m, __shfl_xor(m, o, 64));
  if ((t & 63) == 0) red[t >> 6] = m;
  __syncthreads();
  m = fmaxf(fmaxf(red[0], red[1]), fmaxf(red[2], red[3]));
  float e0 = __expf(v0 - m), e1 = __expf(v1 - m), e2 = __expf(v2 - m), e3 = __expf(v3 - m);
  float s = e0 + e1 + e2 + e3;
  for (int o = 32; o > 0; o >>= 1) s += __shfl_xor(s, o, 64);
  if ((t & 63) == 0) red2[t >> 6] = s;
  __syncthreads();
  s = red2[0] + red2[1] + red2[2] + red2[3];
  float inv = 1.f / s;
  short4v o4;
  o4.x = f2bf(e0 * inv); o4.y = f2bf(e1 * inv); o4.z = f2bf(e2 * inv); o4.w = f2bf(e3 * inv);
  *(short4v*)(p + t * 4) = o4;
}

// ---------------------------------------------------------------- GEMM (bt)
// C[M,N] = A[M,K] * Bt[N,K]^T  (both bf16 row-major, lda=ldb=K), batched over z.
// 128x128 tile, BK=64, 4 waves (2x2), each wave 64x64 via 4x4 mfma 16x16x32.
// LDS staged via global_load_lds w=16, XOR-swizzled (pre-swizzled global src).
#define BM 128
#define BK 64
enum { EPI_TRANS_BF16 = 0, EPI_NORM_BF16 = 1, EPI_RES_F32 = 2 };

__device__ __forceinline__ int swz_idx(int row, int k) {  // short-element index
  return row * 64 + ((((k >> 3) ^ row) & 7) << 3) + (k & 7);
}

template <int EPI>
__global__ __launch_bounds__(256, 2) void gemm_bt(
    const short* __restrict__ A, const short* __restrict__ Bt,
    void* __restrict__ Cv, const float* __restrict__ bias,
    const float* __restrict__ resid, float scale,
    int M, int N, int K, long aStr, long bStr, long cStr, long rStr) {
  __shared__ short lds[2 * BM * BK];  // [0..8191]=A-tile, [8192..]=B-tile
  const int b = blockIdx.z;
  const short* Ab = A + (long)b * aStr;
  const short* Bb = Bt + (long)b * bStr;
  const int m0 = blockIdx.y * BM, n0 = blockIdx.x * BM;
  const int tid = threadIdx.x, lane = tid & 63, w = tid >> 6;
  const int wm = (w >> 1) * 64, wn = (w & 1) * 64;
  f32x4 acc[4][4] = {};

  const int rowst = (w * 4) * 8 + (lane >> 3);  // staging row base for it=0
  for (int k0 = 0; k0 < K; k0 += BK) {
    __syncthreads();
#pragma unroll
    for (int it = 0; it < 4; ++it) {
      int ci = w * 4 + it;
      int row = rowst + it * 8;
      int slot = (lane & 7) ^ (row & 7);
      const short* ga = Ab + (long)(m0 + row) * K + k0 + slot * 8;
      __builtin_amdgcn_global_load_lds(
          (const __attribute__((address_space(1))) void*)ga,
          (__attribute__((address_space(3))) void*)(lds + ci * 512), 16, 0, 0);
      const short* gb = Bb + (long)(n0 + row) * K + k0 + slot * 8;
      __builtin_amdgcn_global_load_lds(
          (const __attribute__((address_space(1))) void*)gb,
          (__attribute__((address_space(3))) void*)(lds + 8192 + ci * 512), 16, 0, 0);
    }
    __syncthreads();
#pragma unroll
    for (int kk = 0; kk < 2; ++kk) {
      short8 af[4], bf[4];
      const int kf = kk * 32 + (lane >> 4) * 8;
#pragma unroll
      for (int i = 0; i < 4; ++i) {
        af[i] = *(const short8*)(lds + swz_idx(wm + i * 16 + (lane & 15), kf));
        bf[i] = *(const short8*)(lds + 8192 + swz_idx(wn + i * 16 + (lane & 15), kf));
      }
#pragma unroll
      for (int i = 0; i < 4; ++i)
#pragma unroll
        for (int j = 0; j < 4; ++j)
          acc[i][j] = __builtin_amdgcn_mfma_f32_16x16x32_bf16(af[i], bf[j], acc[i][j], 0, 0, 0);
    }
  }

  const int mb = m0 + wm + (lane >> 4) * 4;  // + i*16 (+r)
  const int nb = n0 + wn + (lane & 15);      // + j*16
  if constexpr (EPI == EPI_TRANS_BF16) {
    // C^T layout [N][M]: 4 consecutive m per lane -> packed 8B store
    short* C = (short*)Cv + (long)b * cStr;
#pragma unroll
    for (int i = 0; i < 4; ++i) {
      int m = mb + i * 16;
      float b0 = bias[m], b1 = bias[m + 1], b2 = bias[m + 2], b3 = bias[m + 3];
#pragma unroll
      for (int j = 0; j < 4; ++j) {
        int n = nb + j * 16;
        short4v o;
        o.x = f2bf(acc[i][j][0] + b0);
        o.y = f2bf(acc[i][j][1] + b1);
        o.z = f2bf(acc[i][j][2] + b2);
        o.w = f2bf(acc[i][j][3] + b3);
        *(short4v*)(C + (long)n * M + m) = o;
      }
    }
  } else if constexpr (EPI == EPI_NORM_BF16) {
    short* C = (short*)Cv + (long)b * cStr;
#pragma unroll
    for (int i = 0; i < 4; ++i) {
#pragma unroll
      for (int r = 0; r < 4; ++r) {
        int m = mb + i * 16 + r;
        float bi = bias ? bias[m] : 0.f;
#pragma unroll
        for (int j = 0; j < 4; ++j) {
          int n = nb + j * 16;
          C[(long)m * N + n] = f2bf(acc[i][j][r] * scale + bi);
        }
      }
    }
  } else {  // EPI_RES_F32
    float* C = (float*)Cv + (long)b * cStr;
    const float* R = resid + (long)b * rStr;
#pragma unroll
    for (int i = 0; i < 4; ++i) {
#pragma unroll
      for (int r = 0; r < 4; ++r) {
        int m = mb + i * 16 + r;
        float bi = bias[m];
#pragma unroll
        for (int j = 0; j < 4; ++j) {
          int n = nb + j * 16;
          C[(long)m * N + n] = acc[i][j][r] + bi + R[(long)m * N + n];
        }
      }
    }
  }
}

// ---------------------------------------------------------------- launch
extern "C" void kernel_launch(void* const* d_in, const int* in_sizes, int n_in,
                              void* d_out, int out_size, void* d_ws, size_t ws_size,
                              hipStream_t stream) {
  const float* x     = (const float*)d_in[0];
  const float* gamma = (const float*)d_in[1];
  const float* beta  = (const float*)d_in[2];
  const float* wq    = (const float*)d_in[3];
  const float* bq    = (const float*)d_in[4];
  const float* wk    = (const float*)d_in[5];
  const float* bk    = (const float*)d_in[6];
  const float* wv    = (const float*)d_in[7];
  const float* bv    = (const float*)d_in[8];
  const float* wp    = (const float*)d_in[9];
  const float* bp    = (const float*)d_in[10];

  char* ws = (char*)d_ws;
  short* wbf = (short*)ws;                       // 4 x 262144 shorts (2 MB)
  short* xnt = (short*)(ws + 2097152l);          // [B,N,C] bf16, 16 MB
  short* q_t = (short*)(ws + 18874368l);         // [B,N,C]
  short* k_t = (short*)(ws + 35651584l);         // [B,N,C]
  short* vbf = (short*)(ws + 52428800l);         // [B,C,N]
  short* Sbf = (short*)(ws + 69206016l);         // [B,N,N] bf16, 33.5 MB
  short* h_t = xnt;                              // alias (xn dead after v-GEMM)
  // GN partials live at the head of the (not-yet-written) Sbf region
  float2* gnpart = (float2*)Sbf;                 // 1024 float2 = 8 KB

  wcast_kernel<<<1024, 256, 0, stream>>>(wq, wk, wv, wp, wbf);
  gn_stats1<<<1024, 256, 0, stream>>>(x, gnpart);
  gn_norm_t<<<1024, 256, 0, stream>>>(x, gnpart, gamma, beta, xnt);

  const float iscale = 0.044194173824159216f;  // 1/sqrt(512)
  // q_t = (wq . xn^T)^T + bq ; k_t likewise ; v = wv . xn^T + bv
  gemm_bt<EPI_TRANS_BF16><<<dim3(8, 4, 16), 256, 0, stream>>>(
      wbf, xnt, q_t, bq, nullptr, 1.f, 512, 1024, 512, 0, 524288, 524288, 0);
  gemm_bt<EPI_TRANS_BF16><<<dim3(8, 4, 16), 256, 0, stream>>>(
      wbf + 262144, xnt, k_t, bk, nullptr, 1.f, 512, 1024, 512, 0, 524288, 524288, 0);
  gemm_bt<EPI_NORM_BF16><<<dim3(8, 4, 16), 256, 0, stream>>>(
      wbf + 524288, xnt, vbf, bv, nullptr, 1.f, 512, 1024, 512, 0, 524288, 524288, 0);
  // S = (q_t . k_t^T) * scale
  gemm_bt<EPI_NORM_BF16><<<dim3(8, 8, 16), 256, 0, stream>>>(
      q_t, k_t, Sbf, nullptr, nullptr, iscale, 1024, 1024, 512, 524288, 524288, 1048576, 0);
  softmax_kernel<<<16384, 256, 0, stream>>>(Sbf);
  // h_t = P . v^T
  gemm_bt<EPI_NORM_BF16><<<dim3(4, 8, 16), 256, 0, stream>>>(
      Sbf, vbf, h_t, nullptr, nullptr, 1.f, 1024, 512, 1024, 1048576, 524288, 524288, 0);
  // out = wp . h_t^T + bp + x
  gemm_bt<EPI_RES_F32><<<dim3(8, 4, 16), 256, 0, stream>>>(
      wbf + 786432, h_t, d_out, bp, x, 1.f, 512, 1024, 512, 0, 524288, 524288, 524288);
}

// Round 3
// 148.795 us; speedup vs baseline: 1.2698x; 1.1100x over previous
//
#include <hip/hip_runtime.h>

typedef __attribute__((ext_vector_type(8))) short short8;
typedef __attribute__((ext_vector_type(4))) short short4v;
typedef __attribute__((ext_vector_type(4))) float f32x4;

__device__ __forceinline__ short f2bf(float f) {
  unsigned u = __builtin_bit_cast(unsigned, f);
  u = u + 0x7fffu + ((u >> 16) & 1u);
  return (short)(u >> 16);
}
__device__ __forceinline__ float bf2f(short s) {
  unsigned u = ((unsigned)(unsigned short)s) << 16;
  return __builtin_bit_cast(float, u);
}

// ------------------------------------------------ fused: gn_stats + weight cast
// blocks 0..1023: GN partial sums (8192 floats each). blocks 1024..2047: wcast.
__global__ __launch_bounds__(256) void pre_kernel(
    const float* __restrict__ x, float2* __restrict__ part,
    const float* __restrict__ wq, const float* __restrict__ wk,
    const float* __restrict__ wv, const float* __restrict__ wp,
    short* __restrict__ wout) {
  const int blk = blockIdx.x, t = threadIdx.x;
  if (blk < 1024) {
    const float* base = x + (long)blk * 8192;
    float s = 0.f, ss = 0.f;
#pragma unroll
    for (int j = 0; j < 8; ++j) {
      float4 v = ((const float4*)base)[t + j * 256];
      s  += v.x + v.y + v.z + v.w;
      ss += v.x * v.x + v.y * v.y + v.z * v.z + v.w * v.w;
    }
    for (int o = 32; o > 0; o >>= 1) { s += __shfl_xor(s, o, 64); ss += __shfl_xor(ss, o, 64); }
    __shared__ float rs[4], rss[4];
    if ((t & 63) == 0) { rs[t >> 6] = s; rss[t >> 6] = ss; }
    __syncthreads();
    if (t == 0) {
      part[blk] = make_float2(rs[0] + rs[1] + rs[2] + rs[3],
                              rss[0] + rss[1] + rss[2] + rss[3]);
    }
  } else {
    int i = (blk - 1024) * 256 + t;
    wout[i]          = f2bf(wq[i]);
    wout[262144 + i] = f2bf(wk[i]);
    wout[524288 + i] = f2bf(wv[i]);
    wout[786432 + i] = f2bf(wp[i]);
  }
}

// ------------------------------------------------ GN pass 2: normalize+transpose
// grid 1024 = b(16) x g(8) x nc(8); block: 64 channels x 128 tokens.
#define TP 133
__global__ __launch_bounds__(256) void gn_norm_t(
    const float* __restrict__ x, const float2* __restrict__ part,
    const float* __restrict__ gamma, const float* __restrict__ beta,
    short* __restrict__ xnt) {
  const int blk = blockIdx.x;
  const int nc = blk & 7, g = (blk >> 3) & 7, b = blk >> 6;
  const int t = threadIdx.x;
  float s = 0.f, ss = 0.f;
#pragma unroll
  for (int j = 0; j < 8; ++j) {
    float2 p = part[(b * 8 + g) * 8 + j];
    s += p.x; ss += p.y;
  }
  const float mean = s * (1.f / 65536.f);
  const float var  = ss * (1.f / 65536.f) - mean * mean;
  const float rstd = rsqrtf(var + 1e-5f);

  const float* base = x + (long)(b * 512 + g * 64) * 1024 + nc * 128;
  __shared__ float tile[64][TP];
  const int row = t >> 2, c4 = t & 3;
#pragma unroll
  for (int j = 0; j < 8; ++j) {
    float4 v = *(const float4*)(base + (long)row * 1024 + (c4 + j * 4) * 4);
    *(float4*)&tile[row][(c4 + j * 4) * 4] = v;
  }
  const int cl4 = (t & 15) * 4;
  float ga[4], be[4];
#pragma unroll
  for (int j = 0; j < 4; ++j) {
    float gm = gamma[g * 64 + cl4 + j];
    ga[j] = gm * rstd;
    be[j] = beta[g * 64 + cl4 + j] - mean * ga[j];
  }
  __syncthreads();
  short* outb = xnt + (long)b * 524288 + (long)(nc * 128) * 512 + g * 64 + cl4;
#pragma unroll
  for (int it = 0; it < 8; ++it) {
    const int tok = (t >> 4) + it * 16;
    short4v o;
    o.x = f2bf(tile[cl4 + 0][tok] * ga[0] + be[0]);
    o.y = f2bf(tile[cl4 + 1][tok] * ga[1] + be[1]);
    o.z = f2bf(tile[cl4 + 2][tok] * ga[2] + be[2]);
    o.w = f2bf(tile[cl4 + 3][tok] * ga[3] + be[3]);
    *(short4v*)(outb + (long)tok * 512) = o;
  }
}

// ------------------------------------------------ row softmax, 1 wave per row
// grid 4096, block 256 = 4 waves = 4 rows; 16 elems/lane; no LDS.
__global__ __launch_bounds__(256) void softmax_kernel(short* __restrict__ S) {
  const int t = threadIdx.x, lane = t & 63;
  const long row = (long)blockIdx.x * 4 + (t >> 6);
  short* p = S + row * 1024;
  short8 a = *(short8*)(p + lane * 8);
  short8 b = *(short8*)(p + 512 + lane * 8);
  float va[8], vb[8];
  float m = -1e30f;
#pragma unroll
  for (int j = 0; j < 8; ++j) {
    va[j] = bf2f(a[j]); vb[j] = bf2f(b[j]);
    m = fmaxf(m, fmaxf(va[j], vb[j]));
  }
#pragma unroll
  for (int o = 32; o > 0; o >>= 1) m = fmaxf(m, __shfl_xor(m, o, 64));
  float s = 0.f;
#pragma unroll
  for (int j = 0; j < 8; ++j) {
    va[j] = __expf(va[j] - m); vb[j] = __expf(vb[j] - m);
    s += va[j] + vb[j];
  }
#pragma unroll
  for (int o = 32; o > 0; o >>= 1) s += __shfl_xor(s, o, 64);
  const float inv = 1.f / s;
#pragma unroll
  for (int j = 0; j < 8; ++j) { a[j] = f2bf(va[j] * inv); b[j] = f2bf(vb[j] * inv); }
  *(short8*)(p + lane * 8) = a;
  *(short8*)(p + 512 + lane * 8) = b;
}

// ------------------------------------------------ GEMM core (shared main loop)
// C[M,N] = A[M,K] * Bt[N,K]^T, bf16 row-major, 128x128 tile, BK=64, 4 waves.
#define BM 128
#define BK 64
enum { EPI_TRANS_BF16 = 0, EPI_NORM_BF16 = 1, EPI_RES_F32 = 2 };

__device__ __forceinline__ int swz_idx(int row, int k) {
  return row * 64 + ((((k >> 3) ^ row) & 7) << 3) + (k & 7);
}

__device__ __forceinline__ void gemm_core(
    const short* __restrict__ Ab, const short* __restrict__ Bb,
    short* lds, f32x4 (&acc)[4][4], int m0, int n0, int K, int tid) {
  const int lane = tid & 63, w = tid >> 6;
  const int wm = (w >> 1) * 64, wn = (w & 1) * 64;
  const int rowst = w * 32 + (lane >> 3);
  for (int k0 = 0; k0 < K; k0 += BK) {
    __syncthreads();
#pragma unroll
    for (int it = 0; it < 4; ++it) {
      int ci = w * 4 + it;
      int row = rowst + it * 8;
      int slot = (lane & 7) ^ (row & 7);
      const short* ga = Ab + (long)(m0 + row) * K + k0 + slot * 8;
      __builtin_amdgcn_global_load_lds(
          (const __attribute__((address_space(1))) void*)ga,
          (__attribute__((address_space(3))) void*)(lds + ci * 512), 16, 0, 0);
      const short* gb = Bb + (long)(n0 + row) * K + k0 + slot * 8;
      __builtin_amdgcn_global_load_lds(
          (const __attribute__((address_space(1))) void*)gb,
          (__attribute__((address_space(3))) void*)(lds + 8192 + ci * 512), 16, 0, 0);
    }
    __syncthreads();
#pragma unroll
    for (int kk = 0; kk < 2; ++kk) {
      short8 af[4], bf[4];
      const int kf = kk * 32 + (lane >> 4) * 8;
#pragma unroll
      for (int i = 0; i < 4; ++i) {
        af[i] = *(const short8*)(lds + swz_idx(wm + i * 16 + (lane & 15), kf));
        bf[i] = *(const short8*)(lds + 8192 + swz_idx(wn + i * 16 + (lane & 15), kf));
      }
#pragma unroll
      for (int i = 0; i < 4; ++i)
#pragma unroll
        for (int j = 0; j < 4; ++j)
          acc[i][j] = __builtin_amdgcn_mfma_f32_16x16x32_bf16(af[i], bf[j], acc[i][j], 0, 0, 0);
    }
  }
}

// ------------------------------------------------ fused QKV projection GEMM
// W stacked [wq;wk;wv] = [1536,512]. grid (8, 12, 16).
// y 0..3 -> q_t (trans), 4..7 -> k_t (trans), 8..11 -> vbf (norm [512,1024]).
__global__ __launch_bounds__(256, 3) void qkv_gemm(
    const short* __restrict__ W, const short* __restrict__ xnt,
    short* __restrict__ q_t, short* __restrict__ k_t, short* __restrict__ vbf,
    const float* __restrict__ bq, const float* __restrict__ bk,
    const float* __restrict__ bv) {
  __shared__ short lds[2 * BM * BK];
  const int b = blockIdx.z, y = blockIdx.y;
  const int which = y >> 2;
  const int m0 = y * BM;               // in stacked space [0,1536)
  const int mloc0 = m0 - which * 512;  // within the 512-row output
  const int n0 = blockIdx.x * BM;
  const short* Bb = xnt + (long)b * 524288;
  const int tid = threadIdx.x, lane = tid & 63, w = tid >> 6;
  f32x4 acc[4][4] = {};
  gemm_core(W, Bb, lds, acc, m0, n0, 512, tid);

  const int wm = (w >> 1) * 64, wn = (w & 1) * 64;
  const int mb = mloc0 + wm + (lane >> 4) * 4;
  const int nb = n0 + wn + (lane & 15);
  if (which < 2) {
    short* C = (which ? k_t : q_t) + (long)b * 524288;
    const float* bias = which ? bk : bq;
#pragma unroll
    for (int i = 0; i < 4; ++i) {
      int m = mb + i * 16;
      float b0 = bias[m], b1 = bias[m + 1], b2 = bias[m + 2], b3 = bias[m + 3];
#pragma unroll
      for (int j = 0; j < 4; ++j) {
        int n = nb + j * 16;
        short4v o;
        o.x = f2bf(acc[i][j][0] + b0);
        o.y = f2bf(acc[i][j][1] + b1);
        o.z = f2bf(acc[i][j][2] + b2);
        o.w = f2bf(acc[i][j][3] + b3);
        *(short4v*)(C + (long)n * 512 + m) = o;
      }
    }
  } else {
    short* C = vbf + (long)b * 524288;
#pragma unroll
    for (int i = 0; i < 4; ++i) {
#pragma unroll
      for (int r = 0; r < 4; ++r) {
        int m = mb + i * 16 + r;
        float bi = bv[m];
#pragma unroll
        for (int j = 0; j < 4; ++j) {
          int n = nb + j * 16;
          C[(long)m * 1024 + n] = f2bf(acc[i][j][r] + bi);
        }
      }
    }
  }
}

// ------------------------------------------------ generic GEMM (S / PV / out)
template <int EPI>
__global__ __launch_bounds__(256, 3) void gemm_bt(
    const short* __restrict__ A, const short* __restrict__ Bt,
    void* __restrict__ Cv, const float* __restrict__ bias,
    const float* __restrict__ resid, float scale,
    int M, int N, int K, long aStr, long bStr, long cStr, long rStr) {
  __shared__ short lds[2 * BM * BK];
  const int b = blockIdx.z;
  const short* Ab = A + (long)b * aStr;
  const short* Bb = Bt + (long)b * bStr;
  const int m0 = blockIdx.y * BM, n0 = blockIdx.x * BM;
  const int tid = threadIdx.x, lane = tid & 63, w = tid >> 6;
  f32x4 acc[4][4] = {};
  gemm_core(Ab, Bb, lds, acc, m0, n0, K, tid);

  const int wm = (w >> 1) * 64, wn = (w & 1) * 64;
  const int mb = m0 + wm + (lane >> 4) * 4;
  const int nb = n0 + wn + (lane & 15);
  if constexpr (EPI == EPI_NORM_BF16) {
    short* C = (short*)Cv + (long)b * cStr;
#pragma unroll
    for (int i = 0; i < 4; ++i) {
#pragma unroll
      for (int r = 0; r < 4; ++r) {
        int m = mb + i * 16 + r;
        float bi = bias ? bias[m] : 0.f;
#pragma unroll
        for (int j = 0; j < 4; ++j) {
          int n = nb + j * 16;
          C[(long)m * N + n] = f2bf(acc[i][j][r] * scale + bi);
        }
      }
    }
  } else {  // EPI_RES_F32
    float* C = (float*)Cv + (long)b * cStr;
    const float* R = resid + (long)b * rStr;
#pragma unroll
    for (int i = 0; i < 4; ++i) {
#pragma unroll
      for (int r = 0; r < 4; ++r) {
        int m = mb + i * 16 + r;
        float bi = bias[m];
#pragma unroll
        for (int j = 0; j < 4; ++j) {
          int n = nb + j * 16;
          C[(long)m * N + n] = acc[i][j][r] + bi + R[(long)m * N + n];
        }
      }
    }
  }
}

// ---------------------------------------------------------------- launch
extern "C" void kernel_launch(void* const* d_in, const int* in_sizes, int n_in,
                              void* d_out, int out_size, void* d_ws, size_t ws_size,
                              hipStream_t stream) {
  const float* x     = (const float*)d_in[0];
  const float* gamma = (const float*)d_in[1];
  const float* beta  = (const float*)d_in[2];
  const float* wq    = (const float*)d_in[3];
  const float* bq    = (const float*)d_in[4];
  const float* wk    = (const float*)d_in[5];
  const float* bk    = (const float*)d_in[6];
  const float* wv    = (const float*)d_in[7];
  const float* bv    = (const float*)d_in[8];
  const float* wp    = (const float*)d_in[9];
  const float* bp    = (const float*)d_in[10];

  char* ws = (char*)d_ws;
  short* wbf = (short*)ws;                       // [wq;wk;wv;wp] bf16, 2 MB
  short* xnt = (short*)(ws + 2097152l);          // [B,N,C] bf16, 16 MB
  short* q_t = (short*)(ws + 18874368l);         // [B,N,C]
  short* k_t = (short*)(ws + 35651584l);         // [B,N,C]
  short* vbf = (short*)(ws + 52428800l);         // [B,C,N]
  short* Sbf = (short*)(ws + 69206016l);         // [B,N,N] bf16, 33.5 MB
  short* h_t = xnt;                              // alias (xn dead after qkv)
  float2* gnpart = (float2*)Sbf;                 // 8 KB, dead before S written

  pre_kernel<<<2048, 256, 0, stream>>>(x, gnpart, wq, wk, wv, wp, wbf);
  gn_norm_t<<<1024, 256, 0, stream>>>(x, gnpart, gamma, beta, xnt);

  qkv_gemm<<<dim3(8, 12, 16), 256, 0, stream>>>(
      wbf, xnt, q_t, k_t, vbf, bq, bk, bv);

  const float iscale = 0.044194173824159216f;  // 1/sqrt(512)
  gemm_bt<EPI_NORM_BF16><<<dim3(8, 8, 16), 256, 0, stream>>>(
      q_t, k_t, Sbf, nullptr, nullptr, iscale, 1024, 1024, 512, 524288, 524288, 1048576, 0);
  softmax_kernel<<<4096, 256, 0, stream>>>(Sbf);
  gemm_bt<EPI_NORM_BF16><<<dim3(4, 8, 16), 256, 0, stream>>>(
      Sbf, vbf, h_t, nullptr, nullptr, 1.f, 1024, 512, 1024, 1048576, 524288, 524288, 0);
  gemm_bt<EPI_RES_F32><<<dim3(8, 4, 16), 256, 0, stream>>>(
      wbf + 786432, h_t, d_out, bp, x, 1.f, 512, 1024, 512, 0, 524288, 524288, 524288);
}